// Round 1
// baseline (1565.536 us; speedup 1.0000x reference)
//
#include <hip/hip_runtime.h>
#include <cstdint>
#include <cstddef>

static constexpr int DIN  = 128;
static constexpr int DH   = 256;
static constexpr int DOUT = 47;

// ---------------------------------------------------------------------------
// Edge dtype probe: reference declares int64 but harness may hand us int32.
// If int64 (little-endian), words at odd indices (high words) are all 0 for
// values in [0, N). If int32, odd words are random node ids -> ~surely nonzero.
// Probe only the first 4096 entries (8192 words) -- in-bounds either way.
__global__ void k_detect(const int* __restrict__ e, int* __restrict__ flag, int nprobe) {
    int i = blockIdx.x * blockDim.x + threadIdx.x;
    if (i < nprobe) {
        if (e[2 * i + 1] != 0) atomicOr(flag, 1);
    }
}

__global__ void k_hist(const int* __restrict__ e, const int* __restrict__ flag,
                       int* __restrict__ cnt, int E) {
    int i = blockIdx.x * blockDim.x + threadIdx.x;
    if (i >= E) return;
    int is32 = *flag;
    int d = is32 ? e[E + i] : e[2 * (E + i)];
    atomicAdd(&cnt[d], 1);
}

__global__ void k_chunk_sum(const int* __restrict__ cnt, int* __restrict__ csum, int n) {
    int base = blockIdx.x * 1024;
    int t = threadIdx.x;
    int s = 0;
#pragma unroll
    for (int j = 0; j < 4; j++) {
        int i = base + t * 4 + j;
        if (i < n) s += cnt[i];
    }
    __shared__ int red[256];
    red[t] = s;
    __syncthreads();
    for (int off = 128; off > 0; off >>= 1) {
        if (t < off) red[t] += red[t + off];
        __syncthreads();
    }
    if (t == 0) csum[blockIdx.x] = red[0];
}

// exclusive scan over chunk sums (nchunks <= 128), one block of 128 threads
__global__ void k_scan_csum(int* __restrict__ csum, int n,
                            int* __restrict__ rowptr, int N, int E) {
    __shared__ int s[128];
    int t = threadIdx.x;
    int v = (t < n) ? csum[t] : 0;
    s[t] = v;
    __syncthreads();
    for (int off = 1; off < 128; off <<= 1) {
        int xv = (t >= off) ? s[t - off] : 0;
        __syncthreads();
        s[t] += xv;
        __syncthreads();
    }
    if (t < n) csum[t] = s[t] - v;  // exclusive
    if (t == 0) rowptr[N] = E;
}

__global__ void k_scan_apply(const int* __restrict__ cnt, const int* __restrict__ csum,
                             int* __restrict__ rowptr, int n) {
    int base = blockIdx.x * 1024, t = threadIdx.x;
    int i0 = base + t * 4;
    int v[4];
#pragma unroll
    for (int j = 0; j < 4; j++) {
        int i = i0 + j;
        v[j] = (i < n) ? cnt[i] : 0;
    }
    int tsum = v[0] + v[1] + v[2] + v[3];
    __shared__ int s[256];
    s[t] = tsum;
    __syncthreads();
    for (int off = 1; off < 256; off <<= 1) {
        int xv = (t >= off) ? s[t - off] : 0;
        __syncthreads();
        s[t] += xv;
        __syncthreads();
    }
    int excl = s[t] - tsum + csum[blockIdx.x];
#pragma unroll
    for (int j = 0; j < 4; j++) {
        int i = i0 + j;
        if (i < n) rowptr[i] = excl;
        excl += v[j];
    }
}

__global__ void k_fill(const int* __restrict__ e, const int* __restrict__ flag,
                       const int* __restrict__ rowptr, int* __restrict__ cursor,
                       int* __restrict__ colbuf, int E) {
    int i = blockIdx.x * blockDim.x + threadIdx.x;
    if (i >= E) return;
    int is32 = *flag;
    int s = is32 ? e[i] : e[2 * i];
    int d = is32 ? e[E + i] : e[2 * (E + i)];
    int pos = atomicAdd(&cursor[d], 1);
    colbuf[rowptr[d] + pos] = s;
}

__global__ void k_invdeg(const int* __restrict__ rowptr, float* __restrict__ invd, int N) {
    int i = blockIdx.x * blockDim.x + threadIdx.x;
    if (i >= N) return;
    int d = rowptr[i + 1] - rowptr[i];
    invd[i] = 1.0f / (float)(d > 1 ? d : 1);
}

// ---------------------------------------------------------------------------
// CSR mean-aggregation: one wave per destination node, lanes span feature dim.
template <int D>
__global__ void k_agg(const float* __restrict__ X, const int* __restrict__ rowptr,
                      const int* __restrict__ colv, const float* __restrict__ invd,
                      float* __restrict__ out, int N) {
    constexpr int V = D / 64;  // floats per lane
    int wv = threadIdx.x >> 6, lane = threadIdx.x & 63;
    int node = blockIdx.x * 4 + wv;
    if (node >= N) return;
    int beg = rowptr[node], end = rowptr[node + 1];
    float acc[V];
#pragma unroll
    for (int c = 0; c < V; c++) acc[c] = 0.f;
    int j = beg;
    for (; j + 1 < end; j += 2) {
        int s0 = colv[j], s1 = colv[j + 1];
        const float* r0 = X + (size_t)s0 * D + lane * V;
        const float* r1 = X + (size_t)s1 * D + lane * V;
        if constexpr (V == 4) {
            float4 a = *(const float4*)r0;
            float4 b = *(const float4*)r1;
            acc[0] += a.x + b.x; acc[1] += a.y + b.y;
            acc[2] += a.z + b.z; acc[3] += a.w + b.w;
        } else {
            float2 a = *(const float2*)r0;
            float2 b = *(const float2*)r1;
            acc[0] += a.x + b.x; acc[1] += a.y + b.y;
        }
    }
    if (j < end) {
        int s0 = colv[j];
        const float* r0 = X + (size_t)s0 * D + lane * V;
        if constexpr (V == 4) {
            float4 a = *(const float4*)r0;
            acc[0] += a.x; acc[1] += a.y; acc[2] += a.z; acc[3] += a.w;
        } else {
            float2 a = *(const float2*)r0;
            acc[0] += a.x; acc[1] += a.y;
        }
    }
    float sc = invd[node];
    float* o = out + (size_t)node * D + lane * V;
    if constexpr (V == 4) {
        float4 r;
        r.x = acc[0] * sc; r.y = acc[1] * sc; r.z = acc[2] * sc; r.w = acc[3] * sc;
        *(float4*)o = r;
    } else {
        float2 r;
        r.x = acc[0] * sc; r.y = acc[1] * sc;
        *(float2*)o = r;
    }
}

// ---------------------------------------------------------------------------
// Fused dual-A GEMM, full 256-wide output per block (BN=256, BM=64).
// C = relu?( A1@W1 + A2@W2 + bias ). Grid covers rows only, so C may alias A2
// (each block reads only its own rows of A2 in the k-loop, writes in epilogue).
// NOTE: A1/A2/C intentionally NOT __restrict__ (layer 1 runs in-place).
__launch_bounds__(256)
__global__ void k_gemm_wide(const float* A1, const float* A2,
                            const float* __restrict__ W1, const float* __restrict__ W2,
                            const float* __restrict__ bias, float* C,
                            int M, int K, int reluOut) {
    __shared__ float As[16][68];
    __shared__ float Ws[16][256];
    const int t = threadIdx.x;
    const int tx = t & 15, ty = t >> 4;
    const int rowBase = blockIdx.x * 64;
    float acc[4][16];
#pragma unroll
    for (int i = 0; i < 4; i++)
#pragma unroll
        for (int j = 0; j < 16; j++) acc[i][j] = 0.f;

    const int ar = t >> 2, kq = t & 3;
    const int grow = rowBase + ar;

    for (int src = 0; src < 2; src++) {
        const float* A = src ? A2 : A1;
        const float* W = src ? W2 : W1;
        for (int k0 = 0; k0 < K; k0 += 16) {
            float4 av = make_float4(0.f, 0.f, 0.f, 0.f);
            if (grow < M) av = *(const float4*)(A + (size_t)grow * K + k0 + kq * 4);
            float4 wv[4];
#pragma unroll
            for (int p = 0; p < 4; p++) {
                int e = p * 1024 + t * 4;
                wv[p] = *(const float4*)(W + (size_t)(k0 + (e >> 8)) * 256 + (e & 255));
            }
            __syncthreads();
            As[kq * 4 + 0][ar] = av.x;
            As[kq * 4 + 1][ar] = av.y;
            As[kq * 4 + 2][ar] = av.z;
            As[kq * 4 + 3][ar] = av.w;
#pragma unroll
            for (int p = 0; p < 4; p++) {
                int e = p * 1024 + t * 4;
                *(float4*)&Ws[e >> 8][e & 255] = wv[p];
            }
            __syncthreads();
#pragma unroll
            for (int k = 0; k < 16; k++) {
                float4 a = *(const float4*)&As[k][ty * 4];
#pragma unroll
                for (int j = 0; j < 4; j++) {
                    float4 w = *(const float4*)&Ws[k][tx * 4 + 64 * j];
                    acc[0][j * 4 + 0] += a.x * w.x; acc[0][j * 4 + 1] += a.x * w.y;
                    acc[0][j * 4 + 2] += a.x * w.z; acc[0][j * 4 + 3] += a.x * w.w;
                    acc[1][j * 4 + 0] += a.y * w.x; acc[1][j * 4 + 1] += a.y * w.y;
                    acc[1][j * 4 + 2] += a.y * w.z; acc[1][j * 4 + 3] += a.y * w.w;
                    acc[2][j * 4 + 0] += a.z * w.x; acc[2][j * 4 + 1] += a.z * w.y;
                    acc[2][j * 4 + 2] += a.z * w.z; acc[2][j * 4 + 3] += a.z * w.w;
                    acc[3][j * 4 + 0] += a.w * w.x; acc[3][j * 4 + 1] += a.w * w.y;
                    acc[3][j * 4 + 2] += a.w * w.z; acc[3][j * 4 + 3] += a.w * w.w;
                }
            }
        }
    }
#pragma unroll
    for (int i = 0; i < 4; i++) {
        int r = rowBase + ty * 4 + i;
        if (r < M) {
#pragma unroll
            for (int j = 0; j < 4; j++) {
                int cb = tx * 4 + 64 * j;
                float4 b = *(const float4*)(bias + cb);
                float4 o;
                o.x = acc[i][j * 4 + 0] + b.x;
                o.y = acc[i][j * 4 + 1] + b.y;
                o.z = acc[i][j * 4 + 2] + b.z;
                o.w = acc[i][j * 4 + 3] + b.w;
                if (reluOut) {
                    o.x = fmaxf(o.x, 0.f); o.y = fmaxf(o.y, 0.f);
                    o.z = fmaxf(o.z, 0.f); o.w = fmaxf(o.w, 0.f);
                }
                *(float4*)(C + (size_t)r * 256 + cb) = o;
            }
        }
    }
}

// ---------------------------------------------------------------------------
// Narrow GEMM for the 47-wide layer-2 outputs: C = (reluA?relu(A):A) @ W (+bias)
__launch_bounds__(256)
__global__ void k_gemm_small(const float* __restrict__ A, const float* __restrict__ W,
                             const float* __restrict__ bias, float* __restrict__ C,
                             int M, int K, int Dout, int ldc, int reluA) {
    __shared__ float As[16][68];
    __shared__ float Ws[16][64];
    const int t = threadIdx.x;
    const int tx = t & 15, ty = t >> 4;
    const int rowBase = blockIdx.x * 64;
    float acc[4][4];
#pragma unroll
    for (int i = 0; i < 4; i++)
#pragma unroll
        for (int c = 0; c < 4; c++) acc[i][c] = 0.f;

    const int ar = t >> 2, kq = t & 3;
    const int grow = rowBase + ar;
    const int wk = t >> 4, wn = (t & 15) * 4;

    for (int k0 = 0; k0 < K; k0 += 16) {
        float4 av = make_float4(0.f, 0.f, 0.f, 0.f);
        if (grow < M) av = *(const float4*)(A + (size_t)grow * K + k0 + kq * 4);
        if (reluA) {
            av.x = fmaxf(av.x, 0.f); av.y = fmaxf(av.y, 0.f);
            av.z = fmaxf(av.z, 0.f); av.w = fmaxf(av.w, 0.f);
        }
        float w4[4];
#pragma unroll
        for (int c = 0; c < 4; c++) {
            int col = wn + c;
            w4[c] = (col < Dout) ? W[(size_t)(k0 + wk) * Dout + col] : 0.f;
        }
        __syncthreads();
        As[kq * 4 + 0][ar] = av.x;
        As[kq * 4 + 1][ar] = av.y;
        As[kq * 4 + 2][ar] = av.z;
        As[kq * 4 + 3][ar] = av.w;
#pragma unroll
        for (int c = 0; c < 4; c++) Ws[wk][wn + c] = w4[c];
        __syncthreads();
#pragma unroll
        for (int k = 0; k < 16; k++) {
            float4 a = *(const float4*)&As[k][ty * 4];
            float4 w = *(const float4*)&Ws[k][tx * 4];
            acc[0][0] += a.x * w.x; acc[0][1] += a.x * w.y; acc[0][2] += a.x * w.z; acc[0][3] += a.x * w.w;
            acc[1][0] += a.y * w.x; acc[1][1] += a.y * w.y; acc[1][2] += a.y * w.z; acc[1][3] += a.y * w.w;
            acc[2][0] += a.z * w.x; acc[2][1] += a.z * w.y; acc[2][2] += a.z * w.z; acc[2][3] += a.z * w.w;
            acc[3][0] += a.w * w.x; acc[3][1] += a.w * w.y; acc[3][2] += a.w * w.z; acc[3][3] += a.w * w.w;
        }
    }
#pragma unroll
    for (int i = 0; i < 4; i++) {
        int r = rowBase + ty * 4 + i;
        if (r < M) {
#pragma unroll
            for (int c = 0; c < 4; c++) {
                int col = tx * 4 + c;
                if (col < Dout) {
                    float v = acc[i][c];
                    if (bias) v += bias[col];
                    C[(size_t)r * ldc + col] = v;
                }
            }
        }
    }
}

// out0[dst,:] += inv_deg[dst] * sum_{src in N(dst)} U[src,:]   (U has stride 48)
__global__ void k_agg_add47(const float* __restrict__ U, const int* __restrict__ rowptr,
                            const int* __restrict__ colv, const float* __restrict__ invd,
                            float* __restrict__ out0, int N) {
    int wv = threadIdx.x >> 6, lane = threadIdx.x & 63;
    int node = blockIdx.x * 4 + wv;
    if (node >= N) return;
    int beg = rowptr[node], end = rowptr[node + 1];
    float acc = 0.f;
    for (int j = beg; j < end; j++) {
        int s = colv[j];
        if (lane < 48) acc += U[(size_t)s * 48 + lane];
    }
    if (lane < DOUT) {
        out0[(size_t)node * DOUT + lane] += invd[node] * acc;
    }
}

// ---------------------------------------------------------------------------
extern "C" void kernel_launch(void* const* d_in, const int* in_sizes, int n_in,
                              void* d_out, int out_size, void* d_ws, size_t ws_size,
                              hipStream_t stream) {
    const float* x   = (const float*)d_in[0];
    const int*   ei  = (const int*)d_in[1];
    const float* Wl0 = (const float*)d_in[2];
    const float* bl0 = (const float*)d_in[3];
    const float* Wr0 = (const float*)d_in[4];
    const float* Wl1 = (const float*)d_in[5];
    const float* bl1 = (const float*)d_in[6];
    const float* Wr1 = (const float*)d_in[7];
    const float* Wl2 = (const float*)d_in[8];
    const float* bl2 = (const float*)d_in[9];
    const float* Wr2 = (const float*)d_in[10];

    const int N = in_sizes[0] / DIN;
    const int E = in_sizes[1] / 2;

    char* p = (char*)d_ws;
    auto alloc = [&](size_t bytes) -> char* {
        char* r = p;
        p += (bytes + 255) & ~(size_t)255;
        return r;
    };
    int*   flag   = (int*)alloc(4);
    int*   cnt    = (int*)alloc((size_t)N * 4);        // degree histogram, then cursor
    int*   rowptr = (int*)alloc((size_t)(N + 1) * 4);
    int*   csum   = (int*)alloc(1024 * 4);
    int*   colbuf = (int*)alloc((size_t)E * 4);
    float* invd   = (float*)alloc((size_t)N * 4);
    float* aggbuf = (float*)alloc((size_t)N * DH * 4); // agg scratch; later U [N,48]

    float* out0 = (float*)d_out;                       // [N,47]
    float* hbuf = (float*)d_out + (size_t)N * DOUT;    // [N,256]: h0, then h_out in-place

    hipMemsetAsync(flag, 0, 4, stream);
    hipMemsetAsync(cnt, 0, (size_t)N * 4, stream);

    const int nprobe = 4096;
    k_detect<<<(nprobe + 255) / 256, 256, 0, stream>>>(ei, flag, nprobe);
    k_hist<<<(E + 255) / 256, 256, 0, stream>>>(ei, flag, cnt, E);

    const int nchunks = (N + 1023) / 1024;
    k_chunk_sum<<<nchunks, 256, 0, stream>>>(cnt, csum, N);
    k_scan_csum<<<1, 128, 0, stream>>>(csum, nchunks, rowptr, N, E);
    k_scan_apply<<<nchunks, 256, 0, stream>>>(cnt, csum, rowptr, N);
    hipMemsetAsync(cnt, 0, (size_t)N * 4, stream);
    k_fill<<<(E + 255) / 256, 256, 0, stream>>>(ei, flag, rowptr, cnt, colbuf, E);
    k_invdeg<<<(N + 255) / 256, 256, 0, stream>>>(rowptr, invd, N);

    const int aggBlocks = (N + 3) / 4;
    const int gw = (N + 63) / 64;

    // Layer 0: aggregate x (128-wide), fused GEMM -> h0 = relu(agg@Wl0 + bl0 + x@Wr0)
    k_agg<128><<<aggBlocks, 256, 0, stream>>>(x, rowptr, colbuf, invd, aggbuf, N);
    k_gemm_wide<<<gw, 256, 0, stream>>>(aggbuf, x, Wl0, Wr0, bl0, hbuf, N, 128, 1);

    // Layer 1: aggregate h0 (256-wide), fused GEMM in-place -> h_out (output 1, pre-ReLU)
    k_agg<256><<<aggBlocks, 256, 0, stream>>>(hbuf, rowptr, colbuf, invd, aggbuf, N);
    k_gemm_wide<<<gw, 256, 0, stream>>>(aggbuf, hbuf, Wl1, Wr1, bl1, hbuf, N, 256, 0);

    // Layer 2: aggregate AFTER the GEMM (47-wide instead of 256-wide scatter):
    //   u = relu(h_out) @ Wl2 ; out0 = relu(h_out) @ Wr2 + bl2 ; out0 += mean-agg(u)
    float* ubuf = aggbuf;  // reuse, stride 48
    k_gemm_small<<<gw, 256, 0, stream>>>(hbuf, Wl2, nullptr, ubuf, N, 256, DOUT, 48, 1);
    k_gemm_small<<<gw, 256, 0, stream>>>(hbuf, Wr2, bl2, out0, N, 256, DOUT, DOUT, 1);
    k_agg_add47<<<aggBlocks, 256, 0, stream>>>(ubuf, rowptr, colbuf, invd, out0, N);
}

// Round 2
// 878.985 us; speedup vs baseline: 1.7811x; 1.7811x over previous
//
#include <hip/hip_runtime.h>
#include <cstdint>
#include <cstddef>

static constexpr int DIN  = 128;
static constexpr int DH   = 256;
static constexpr int DOUT = 47;

typedef __attribute__((ext_vector_type(8))) short bf16x8;
typedef __attribute__((ext_vector_type(4))) float f32x4;

__device__ __forceinline__ short f2bf(float f) {
    unsigned u = __float_as_uint(f);
    unsigned r = (u + 0x7fffu + ((u >> 16) & 1u)) >> 16;  // RNE
    return (short)r;
}
__device__ __forceinline__ float bflo(unsigned u) { return __uint_as_float(u << 16); }
__device__ __forceinline__ float bfhi(unsigned u) { return __uint_as_float(u & 0xffff0000u); }
__device__ __forceinline__ float bf1(unsigned short s) { return __uint_as_float((unsigned)s << 16); }

// ---------------------------------------------------------------------------
// CSR build (unchanged from round 1)
__global__ void k_detect(const int* __restrict__ e, int* __restrict__ flag, int nprobe) {
    int i = blockIdx.x * blockDim.x + threadIdx.x;
    if (i < nprobe) {
        if (e[2 * i + 1] != 0) atomicOr(flag, 1);
    }
}

__global__ void k_hist(const int* __restrict__ e, const int* __restrict__ flag,
                       int* __restrict__ cnt, int E) {
    int i = blockIdx.x * blockDim.x + threadIdx.x;
    if (i >= E) return;
    int is32 = *flag;
    int d = is32 ? e[E + i] : e[2 * (E + i)];
    atomicAdd(&cnt[d], 1);
}

__global__ void k_chunk_sum(const int* __restrict__ cnt, int* __restrict__ csum, int n) {
    int base = blockIdx.x * 1024;
    int t = threadIdx.x;
    int s = 0;
#pragma unroll
    for (int j = 0; j < 4; j++) {
        int i = base + t * 4 + j;
        if (i < n) s += cnt[i];
    }
    __shared__ int red[256];
    red[t] = s;
    __syncthreads();
    for (int off = 128; off > 0; off >>= 1) {
        if (t < off) red[t] += red[t + off];
        __syncthreads();
    }
    if (t == 0) csum[blockIdx.x] = red[0];
}

__global__ void k_scan_csum(int* __restrict__ csum, int n,
                            int* __restrict__ rowptr, int N, int E) {
    __shared__ int s[128];
    int t = threadIdx.x;
    int v = (t < n) ? csum[t] : 0;
    s[t] = v;
    __syncthreads();
    for (int off = 1; off < 128; off <<= 1) {
        int xv = (t >= off) ? s[t - off] : 0;
        __syncthreads();
        s[t] += xv;
        __syncthreads();
    }
    if (t < n) csum[t] = s[t] - v;  // exclusive
    if (t == 0) rowptr[N] = E;
}

__global__ void k_scan_apply(const int* __restrict__ cnt, const int* __restrict__ csum,
                             int* __restrict__ rowptr, int n) {
    int base = blockIdx.x * 1024, t = threadIdx.x;
    int i0 = base + t * 4;
    int v[4];
#pragma unroll
    for (int j = 0; j < 4; j++) {
        int i = i0 + j;
        v[j] = (i < n) ? cnt[i] : 0;
    }
    int tsum = v[0] + v[1] + v[2] + v[3];
    __shared__ int s[256];
    s[t] = tsum;
    __syncthreads();
    for (int off = 1; off < 256; off <<= 1) {
        int xv = (t >= off) ? s[t - off] : 0;
        __syncthreads();
        s[t] += xv;
        __syncthreads();
    }
    int excl = s[t] - tsum + csum[blockIdx.x];
#pragma unroll
    for (int j = 0; j < 4; j++) {
        int i = i0 + j;
        if (i < n) rowptr[i] = excl;
        excl += v[j];
    }
}

__global__ void k_fill(const int* __restrict__ e, const int* __restrict__ flag,
                       const int* __restrict__ rowptr, int* __restrict__ cursor,
                       int* __restrict__ colbuf, int E) {
    int i = blockIdx.x * blockDim.x + threadIdx.x;
    if (i >= E) return;
    int is32 = *flag;
    int s = is32 ? e[i] : e[2 * i];
    int d = is32 ? e[E + i] : e[2 * (E + i)];
    int pos = atomicAdd(&cursor[d], 1);
    colbuf[rowptr[d] + pos] = s;
}

__global__ void k_invdeg(const int* __restrict__ rowptr, float* __restrict__ invd, int N) {
    int i = blockIdx.x * blockDim.x + threadIdx.x;
    if (i >= N) return;
    int d = rowptr[i + 1] - rowptr[i];
    invd[i] = 1.0f / (float)(d > 1 ? d : 1);
}

// ---------------------------------------------------------------------------
// fp32 -> bf16 convert (x)
__global__ void k_f2bf(const float* __restrict__ X, short* __restrict__ Y, int n4) {
    int i = blockIdx.x * 256 + threadIdx.x;
    if (i >= n4) return;
    float4 v = *(const float4*)(X + (size_t)i * 4);
    short4 o;
    o.x = f2bf(v.x); o.y = f2bf(v.y); o.z = f2bf(v.z); o.w = f2bf(v.w);
    *(short4*)(Y + (size_t)i * 4) = o;
}

// ---------------------------------------------------------------------------
// Pack fp32 weight [K, Ncols] into bf16 B-fragment order for mfma_16x16x32:
// P[((ks*Nt + nt)*64 + lane)*8 + j] = W[ks*32 + (lane>>4)*8 + j][nt*16 + (lane&15)]
__global__ void k_pack(const float* __restrict__ W, short* __restrict__ P,
                       int ksteps, int Nt, int Ncols) {
    int idx = blockIdx.x * 256 + threadIdx.x;
    int total = ksteps * Nt * 64;
    if (idx >= total) return;
    int lane = idx & 63;
    int t = idx >> 6;
    int nt = t % Nt;
    int ks = t / Nt;
    int n = nt * 16 + (lane & 15);
    int kb = ks * 32 + (lane >> 4) * 8;
    bf16x8 o;
#pragma unroll
    for (int j = 0; j < 8; j++)
        o[j] = (n < Ncols) ? f2bf(W[(size_t)(kb + j) * Ncols + n]) : (short)0;
    *(bf16x8*)(P + (size_t)idx * 8) = o;
}

// ---------------------------------------------------------------------------
// CSR mean-aggregation over bf16 rows. One wave per destination node.
template <int D>  // 128 -> 2 bf16/lane, 256 -> 4 bf16/lane
__global__ void k_agg_bf(const short* __restrict__ X, const int* __restrict__ rowptr,
                         const int* __restrict__ colv, const float* __restrict__ invd,
                         short* __restrict__ out, int N) {
    constexpr int V = D / 64;
    int wv = threadIdx.x >> 6, lane = threadIdx.x & 63;
    int node = blockIdx.x * 4 + wv;
    if (node >= N) return;
    int beg = rowptr[node], end = rowptr[node + 1];
    float acc[V];
#pragma unroll
    for (int c = 0; c < V; c++) acc[c] = 0.f;
    int j = beg;
    for (; j + 1 < end; j += 2) {
        int s0 = colv[j], s1 = colv[j + 1];
        if constexpr (V == 2) {
            unsigned a = *(const unsigned*)(X + (size_t)s0 * D + lane * 2);
            unsigned b = *(const unsigned*)(X + (size_t)s1 * D + lane * 2);
            acc[0] += bflo(a) + bflo(b);
            acc[1] += bfhi(a) + bfhi(b);
        } else {
            uint2 a = *(const uint2*)(X + (size_t)s0 * D + lane * 4);
            uint2 b = *(const uint2*)(X + (size_t)s1 * D + lane * 4);
            acc[0] += bflo(a.x) + bflo(b.x);
            acc[1] += bfhi(a.x) + bfhi(b.x);
            acc[2] += bflo(a.y) + bflo(b.y);
            acc[3] += bfhi(a.y) + bfhi(b.y);
        }
    }
    if (j < end) {
        int s0 = colv[j];
        if constexpr (V == 2) {
            unsigned a = *(const unsigned*)(X + (size_t)s0 * D + lane * 2);
            acc[0] += bflo(a);
            acc[1] += bfhi(a);
        } else {
            uint2 a = *(const uint2*)(X + (size_t)s0 * D + lane * 4);
            acc[0] += bflo(a.x);
            acc[1] += bfhi(a.x);
            acc[2] += bflo(a.y);
            acc[3] += bfhi(a.y);
        }
    }
    float sc = invd[node];
    if constexpr (V == 2) {
        unsigned o = (unsigned)(unsigned short)f2bf(acc[0] * sc) |
                     ((unsigned)(unsigned short)f2bf(acc[1] * sc) << 16);
        *(unsigned*)(out + (size_t)node * D + lane * 2) = o;
    } else {
        uint2 o;
        o.x = (unsigned)(unsigned short)f2bf(acc[0] * sc) |
              ((unsigned)(unsigned short)f2bf(acc[1] * sc) << 16);
        o.y = (unsigned)(unsigned short)f2bf(acc[2] * sc) |
              ((unsigned)(unsigned short)f2bf(acc[3] * sc) << 16);
        *(uint2*)(out + (size_t)node * D + lane * 4) = o;
    }
}

// ---------------------------------------------------------------------------
// LDS-free dual-A bf16 MFMA GEMM: S = A1@W1 + A2@W2 + bias  (N = 256 fixed)
// Block: 256 threads = 4 waves. Block covers 64 rows; wave w covers cols [w*64, w*64+64).
// A row-major bf16 => A-frag (m=lane&15, k=quad*8+j) is one contiguous 16B load.
// P* pre-packed in B-frag order => one coalesced 16B load per lane.
// Cf (fp32, raw S) and Cb (bf16, relu(S)) optional. Cb may alias A2 (in-place):
// the __syncthreads() between K-loop and epilogue makes that safe within the
// block, and each block only reads/writes its own 64 rows.
__launch_bounds__(256)
__global__ void k_gemm_mfma_wide(const short* __restrict__ A1, const short* A2,
                                 const short* __restrict__ P1, const short* __restrict__ P2,
                                 const float* __restrict__ bias,
                                 float* Cf, short* Cb, int M, int K1, int K2) {
    const int lane = threadIdx.x & 63;
    const int wave = threadIdx.x >> 6;
    const int quad = lane >> 4;
    const int r    = lane & 15;
    const int rowBase = blockIdx.x * 64;

    f32x4 acc[4][4];  // [m-tile][n-tile]
#pragma unroll
    for (int mt = 0; mt < 4; mt++)
#pragma unroll
        for (int nt = 0; nt < 4; nt++) acc[mt][nt] = (f32x4)(0.f);

    int arow[4];
#pragma unroll
    for (int mt = 0; mt < 4; mt++) {
        int row = rowBase + mt * 16 + r;
        arow[mt] = row < M ? row : M - 1;  // clamped rows are masked at store
    }

    for (int src = 0; src < 2; src++) {
        const short* A = src ? A2 : A1;
        const short* P = src ? P2 : P1;
        const int K = src ? K2 : K1;
        const int nks = K >> 5;
        for (int ks = 0; ks < nks; ks++) {
            bf16x8 af[4], bfr[4];
#pragma unroll
            for (int mt = 0; mt < 4; mt++)
                af[mt] = *(const bf16x8*)(A + (size_t)arow[mt] * K + ks * 32 + quad * 8);
#pragma unroll
            for (int nt = 0; nt < 4; nt++)
                bfr[nt] = *(const bf16x8*)(P + (((size_t)(ks * 16 + wave * 4 + nt) * 64 + lane) << 3));
#pragma unroll
            for (int mt = 0; mt < 4; mt++)
#pragma unroll
                for (int nt = 0; nt < 4; nt++)
                    acc[mt][nt] = __builtin_amdgcn_mfma_f32_16x16x32_bf16(
                        af[mt], bfr[nt], acc[mt][nt], 0, 0, 0);
        }
    }

    __syncthreads();  // guard in-place Cb == A2

    float bv[4];
#pragma unroll
    for (int nt = 0; nt < 4; nt++) bv[nt] = bias[wave * 64 + nt * 16 + r];

#pragma unroll
    for (int mt = 0; mt < 4; mt++) {
#pragma unroll
        for (int reg = 0; reg < 4; reg++) {
            int row = rowBase + mt * 16 + quad * 4 + reg;
            if (row >= M) continue;
#pragma unroll
            for (int nt = 0; nt < 4; nt++) {
                int col = wave * 64 + nt * 16 + r;
                float v = acc[mt][nt][reg] + bv[nt];
                if (Cf) Cf[(size_t)row * 256 + col] = v;
                if (Cb) Cb[(size_t)row * 256 + col] = f2bf(fmaxf(v, 0.f));
            }
        }
    }
}

// ---------------------------------------------------------------------------
// Layer-2 fused dual-W MFMA: reads hrelu (bf16, K=256) once,
//   U   = hrelu @ Wl2        (bf16, [M,48] padded stride)
//   Out = hrelu @ Wr2 + bl2  (fp32, [M,47])
// Block 256 thr = 4 waves; wave w covers rows [blk*256 + w*64, +64), 48 cols (3 n-tiles).
__launch_bounds__(256)
__global__ void k_gemm_mfma_out(const short* __restrict__ A,
                                const short* __restrict__ Pl, const short* __restrict__ Pr,
                                const float* __restrict__ bias,
                                short* __restrict__ U, float* __restrict__ Out, int M) {
    const int lane = threadIdx.x & 63;
    const int wave = threadIdx.x >> 6;
    const int quad = lane >> 4;
    const int r    = lane & 15;
    const int rowBase = blockIdx.x * 256 + wave * 64;

    f32x4 aU[4][3], aO[4][3];
#pragma unroll
    for (int mt = 0; mt < 4; mt++)
#pragma unroll
        for (int nt = 0; nt < 3; nt++) { aU[mt][nt] = (f32x4)(0.f); aO[mt][nt] = (f32x4)(0.f); }

    int arow[4];
#pragma unroll
    for (int mt = 0; mt < 4; mt++) {
        int row = rowBase + mt * 16 + r;
        arow[mt] = row < M ? row : M - 1;
    }

    for (int ks = 0; ks < 8; ks++) {
        bf16x8 af[4], bl[3], br[3];
#pragma unroll
        for (int mt = 0; mt < 4; mt++)
            af[mt] = *(const bf16x8*)(A + (size_t)arow[mt] * 256 + ks * 32 + quad * 8);
#pragma unroll
        for (int nt = 0; nt < 3; nt++) {
            size_t fo = (((size_t)(ks * 3 + nt) * 64 + lane) << 3);
            bl[nt] = *(const bf16x8*)(Pl + fo);
            br[nt] = *(const bf16x8*)(Pr + fo);
        }
#pragma unroll
        for (int mt = 0; mt < 4; mt++)
#pragma unroll
            for (int nt = 0; nt < 3; nt++) {
                aU[mt][nt] = __builtin_amdgcn_mfma_f32_16x16x32_bf16(af[mt], bl[nt], aU[mt][nt], 0, 0, 0);
                aO[mt][nt] = __builtin_amdgcn_mfma_f32_16x16x32_bf16(af[mt], br[nt], aO[mt][nt], 0, 0, 0);
            }
    }

    float bv[3];
#pragma unroll
    for (int nt = 0; nt < 3; nt++) {
        int col = nt * 16 + r;
        bv[nt] = (col < DOUT) ? bias[col] : 0.f;
    }

#pragma unroll
    for (int mt = 0; mt < 4; mt++) {
#pragma unroll
        for (int reg = 0; reg < 4; reg++) {
            int row = rowBase + mt * 16 + quad * 4 + reg;
            if (row >= M) continue;
#pragma unroll
            for (int nt = 0; nt < 3; nt++) {
                int col = nt * 16 + r;
                U[(size_t)row * 48 + col] = f2bf(aU[mt][nt][reg]);
                if (col < DOUT) Out[(size_t)row * DOUT + col] = aO[mt][nt][reg] + bv[nt];
            }
        }
    }
}

// out0[dst,:] += inv_deg[dst] * sum_{src in N(dst)} U[src,:]  (U bf16, stride 48)
__global__ void k_agg_add47(const short* __restrict__ U, const int* __restrict__ rowptr,
                            const int* __restrict__ colv, const float* __restrict__ invd,
                            float* __restrict__ out0, int N) {
    int wv = threadIdx.x >> 6, lane = threadIdx.x & 63;
    int node = blockIdx.x * 4 + wv;
    if (node >= N) return;
    int beg = rowptr[node], end = rowptr[node + 1];
    float acc = 0.f;
    int j = beg;
    for (; j + 1 < end; j += 2) {
        int s0 = colv[j], s1 = colv[j + 1];
        if (lane < 48) {
            acc += bf1(((const unsigned short*)U)[(size_t)s0 * 48 + lane]);
            acc += bf1(((const unsigned short*)U)[(size_t)s1 * 48 + lane]);
        }
    }
    if (j < end && lane < 48) {
        acc += bf1(((const unsigned short*)U)[(size_t)colv[j] * 48 + lane]);
    }
    if (lane < DOUT) {
        out0[(size_t)node * DOUT + lane] += invd[node] * acc;
    }
}

// ---------------------------------------------------------------------------
extern "C" void kernel_launch(void* const* d_in, const int* in_sizes, int n_in,
                              void* d_out, int out_size, void* d_ws, size_t ws_size,
                              hipStream_t stream) {
    const float* x   = (const float*)d_in[0];
    const int*   ei  = (const int*)d_in[1];
    const float* Wl0 = (const float*)d_in[2];
    const float* bl0 = (const float*)d_in[3];
    const float* Wr0 = (const float*)d_in[4];
    const float* Wl1 = (const float*)d_in[5];
    const float* bl1 = (const float*)d_in[6];
    const float* Wr1 = (const float*)d_in[7];
    const float* Wl2 = (const float*)d_in[8];
    const float* bl2 = (const float*)d_in[9];
    const float* Wr2 = (const float*)d_in[10];

    const int N = in_sizes[0] / DIN;
    const int E = in_sizes[1] / 2;

    char* p = (char*)d_ws;
    auto alloc = [&](size_t bytes) -> char* {
        char* r = p;
        p += (bytes + 255) & ~(size_t)255;
        return r;
    };
    int*   flag   = (int*)alloc(4);
    int*   cnt    = (int*)alloc((size_t)N * 4);
    int*   rowptr = (int*)alloc((size_t)(N + 1) * 4);
    int*   csum   = (int*)alloc(1024 * 4);
    int*   colbuf = (int*)alloc((size_t)E * 4);
    float* invd   = (float*)alloc((size_t)N * 4);
    short* xbf    = (short*)alloc((size_t)N * DIN * 2);   // x bf16; later reused as U [N,48]
    short* bufA   = (short*)alloc((size_t)N * DH * 2);    // agg scratch (128- or 256-wide)
    short* h0     = (short*)alloc((size_t)N * DH * 2);    // h0 bf16; hrelu in-place after L1
    short* Pl0    = (short*)alloc((size_t)DIN * 256 * 2);
    short* Pr0    = (short*)alloc((size_t)DIN * 256 * 2);
    short* Pl1    = (short*)alloc((size_t)DH * 256 * 2);
    short* Pr1    = (short*)alloc((size_t)DH * 256 * 2);
    short* Pl2    = (short*)alloc((size_t)DH * 48 * 2);
    short* Pr2    = (short*)alloc((size_t)DH * 48 * 2);

    float* out0 = (float*)d_out;                        // [N,47]
    float* hout = (float*)d_out + (size_t)N * DOUT;     // [N,256] fp32 (output 1)

    hipMemsetAsync(flag, 0, 4, stream);
    hipMemsetAsync(cnt, 0, (size_t)N * 4, stream);

    // --- CSR build ---
    const int nprobe = E < 4096 ? E : 4096;
    k_detect<<<(nprobe + 255) / 256, 256, 0, stream>>>(ei, flag, nprobe);
    k_hist<<<(E + 255) / 256, 256, 0, stream>>>(ei, flag, cnt, E);
    const int nchunks = (N + 1023) / 1024;
    k_chunk_sum<<<nchunks, 256, 0, stream>>>(cnt, csum, N);
    k_scan_csum<<<1, 128, 0, stream>>>(csum, nchunks, rowptr, N, E);
    k_scan_apply<<<nchunks, 256, 0, stream>>>(cnt, csum, rowptr, N);
    hipMemsetAsync(cnt, 0, (size_t)N * 4, stream);
    k_fill<<<(E + 255) / 256, 256, 0, stream>>>(ei, flag, rowptr, cnt, colbuf, E);
    k_invdeg<<<(N + 255) / 256, 256, 0, stream>>>(rowptr, invd, N);

    // --- weight packing (tiny) + x conversion ---
    k_pack<<<(4 * 16 * 64 + 255) / 256, 256, 0, stream>>>(Wl0, Pl0, 4, 16, 256);
    k_pack<<<(4 * 16 * 64 + 255) / 256, 256, 0, stream>>>(Wr0, Pr0, 4, 16, 256);
    k_pack<<<(8 * 16 * 64 + 255) / 256, 256, 0, stream>>>(Wl1, Pl1, 8, 16, 256);
    k_pack<<<(8 * 16 * 64 + 255) / 256, 256, 0, stream>>>(Wr1, Pr1, 8, 16, 256);
    k_pack<<<(8 * 3 * 64 + 255) / 256, 256, 0, stream>>>(Wl2, Pl2, 8, 3, DOUT);
    k_pack<<<(8 * 3 * 64 + 255) / 256, 256, 0, stream>>>(Wr2, Pr2, 8, 3, DOUT);
    k_f2bf<<<((N * DIN / 4) + 255) / 256, 256, 0, stream>>>(x, xbf, N * DIN / 4);

    const int aggBlocks = (N + 3) / 4;
    const int gw = (N + 63) / 64;

    // Layer 0: h0 = bf16(relu(agg(x)@Wl0 + bl0 + x@Wr0))
    k_agg_bf<128><<<aggBlocks, 256, 0, stream>>>(xbf, rowptr, colbuf, invd, bufA, N);
    k_gemm_mfma_wide<<<gw, 256, 0, stream>>>(bufA, xbf, Pl0, Pr0, bl0, nullptr, h0,
                                             N, DIN, DIN);

    // Layer 1: hout(fp32, output 1) = agg(h0)@Wl1 + bl1 + h0@Wr1 ; hrelu = bf16(relu(.)) in-place over h0
    k_agg_bf<256><<<aggBlocks, 256, 0, stream>>>(h0, rowptr, colbuf, invd, bufA, N);
    k_gemm_mfma_wide<<<gw, 256, 0, stream>>>(bufA, h0, Pl1, Pr1, bl1, hout, h0,
                                             N, DH, DH);

    // Layer 2: u = hrelu@Wl2 (bf16), out0 = hrelu@Wr2 + bl2; then out0 += agg(u)
    short* U = xbf;  // xbf dead; [N,48] fits in [N,128] region
    k_gemm_mfma_out<<<(N + 255) / 256, 256, 0, stream>>>(h0, Pl2, Pr2, bl2, U, out0, N);
    k_agg_add47<<<aggBlocks, 256, 0, stream>>>(U, rowptr, colbuf, invd, out0, N);
}

// Round 3
// 768.113 us; speedup vs baseline: 2.0382x; 1.1443x over previous
//
#include <hip/hip_runtime.h>
#include <cstdint>
#include <cstddef>

static constexpr int DIN  = 128;
static constexpr int DH   = 256;
static constexpr int DOUT = 47;

typedef __attribute__((ext_vector_type(8))) short bf16x8;
typedef __attribute__((ext_vector_type(4))) float f32x4;

__device__ __forceinline__ short f2bf(float f) {
    unsigned u = __float_as_uint(f);
    unsigned r = (u + 0x7fffu + ((u >> 16) & 1u)) >> 16;  // RNE
    return (short)r;
}
__device__ __forceinline__ float bflo(unsigned u) { return __uint_as_float(u << 16); }
__device__ __forceinline__ float bfhi(unsigned u) { return __uint_as_float(u & 0xffff0000u); }

// ---------------------------------------------------------------------------
// CSR build
__global__ void k_detect(const int* __restrict__ e, int* __restrict__ flag, int nprobe) {
    int i = blockIdx.x * blockDim.x + threadIdx.x;
    if (i < nprobe) {
        if (e[2 * i + 1] != 0) atomicOr(flag, 1);
    }
}

__global__ void k_hist(const int* __restrict__ e, const int* __restrict__ flag,
                       int* __restrict__ cnt, int E) {
    int i = blockIdx.x * blockDim.x + threadIdx.x;
    if (i >= E) return;
    int is32 = *flag;
    int d = is32 ? e[E + i] : e[2 * (E + i)];
    atomicAdd(&cnt[d], 1);
}

__global__ void k_chunk_sum(const int* __restrict__ cnt, int* __restrict__ csum, int n) {
    int base = blockIdx.x * 1024;
    int t = threadIdx.x;
    int s = 0;
#pragma unroll
    for (int j = 0; j < 4; j++) {
        int i = base + t * 4 + j;
        if (i < n) s += cnt[i];
    }
    __shared__ int red[256];
    red[t] = s;
    __syncthreads();
    for (int off = 128; off > 0; off >>= 1) {
        if (t < off) red[t] += red[t + off];
        __syncthreads();
    }
    if (t == 0) csum[blockIdx.x] = red[0];
}

__global__ void k_scan_csum(int* __restrict__ csum, int n,
                            int* __restrict__ rowptr, int N, int E) {
    __shared__ int s[128];
    int t = threadIdx.x;
    int v = (t < n) ? csum[t] : 0;
    s[t] = v;
    __syncthreads();
    for (int off = 1; off < 128; off <<= 1) {
        int xv = (t >= off) ? s[t - off] : 0;
        __syncthreads();
        s[t] += xv;
        __syncthreads();
    }
    if (t < n) csum[t] = s[t] - v;  // exclusive
    if (t == 0) rowptr[N] = E;
}

__global__ void k_scan_apply(const int* __restrict__ cnt, const int* __restrict__ csum,
                             int* __restrict__ rowptr, int n) {
    int base = blockIdx.x * 1024, t = threadIdx.x;
    int i0 = base + t * 4;
    int v[4];
#pragma unroll
    for (int j = 0; j < 4; j++) {
        int i = i0 + j;
        v[j] = (i < n) ? cnt[i] : 0;
    }
    int tsum = v[0] + v[1] + v[2] + v[3];
    __shared__ int s[256];
    s[t] = tsum;
    __syncthreads();
    for (int off = 1; off < 256; off <<= 1) {
        int xv = (t >= off) ? s[t - off] : 0;
        __syncthreads();
        s[t] += xv;
        __syncthreads();
    }
    int excl = s[t] - tsum + csum[blockIdx.x];
#pragma unroll
    for (int j = 0; j < 4; j++) {
        int i = i0 + j;
        if (i < n) rowptr[i] = excl;
        excl += v[j];
    }
}

__global__ void k_fill(const int* __restrict__ e, const int* __restrict__ flag,
                       const int* __restrict__ rowptr, int* __restrict__ cursor,
                       int* __restrict__ colbuf, int E) {
    int i = blockIdx.x * blockDim.x + threadIdx.x;
    if (i >= E) return;
    int is32 = *flag;
    int s = is32 ? e[i] : e[2 * i];
    int d = is32 ? e[E + i] : e[2 * (E + i)];
    int pos = atomicAdd(&cursor[d], 1);
    colbuf[rowptr[d] + pos] = s;
}

__global__ void k_invdeg(const int* __restrict__ rowptr, float* __restrict__ invd, int N) {
    int i = blockIdx.x * blockDim.x + threadIdx.x;
    if (i >= N) return;
    int d = rowptr[i + 1] - rowptr[i];
    invd[i] = 1.0f / (float)(d > 1 ? d : 1);
}

// ---------------------------------------------------------------------------
__global__ void k_f2bf(const float* __restrict__ X, short* __restrict__ Y, int n4) {
    int i = blockIdx.x * 256 + threadIdx.x;
    if (i >= n4) return;
    float4 v = *(const float4*)(X + (size_t)i * 4);
    short4 o;
    o.x = f2bf(v.x); o.y = f2bf(v.y); o.z = f2bf(v.z); o.w = f2bf(v.w);
    *(short4*)(Y + (size_t)i * 4) = o;
}

// Pack fp32 weight [K, Ncols] into bf16 B-fragment order for mfma_16x16x32
__global__ void k_pack(const float* __restrict__ W, short* __restrict__ P,
                       int ksteps, int Nt, int Ncols) {
    int idx = blockIdx.x * 256 + threadIdx.x;
    int total = ksteps * Nt * 64;
    if (idx >= total) return;
    int lane = idx & 63;
    int t = idx >> 6;
    int nt = t % Nt;
    int ks = t / Nt;
    int n = nt * 16 + (lane & 15);
    int kb = ks * 32 + (lane >> 4) * 8;
    bf16x8 o;
#pragma unroll
    for (int j = 0; j < 8; j++)
        o[j] = (n < Ncols) ? f2bf(W[(size_t)(kb + j) * Ncols + n]) : (short)0;
    *(bf16x8*)(P + (size_t)idx * 8) = o;
}

// ---------------------------------------------------------------------------
// 256-wide CSR mean-agg, MLP-optimized: half-wave owns a neighbor row
// (32 lanes x 16B = 512B), 8 neighbors per unrolled iter (4 gathers in flight),
// wave-uniform index fetches (s_load), cross-half combine via shfl_xor(32).
__launch_bounds__(256)
__global__ void k_agg256(const short* __restrict__ X, const int* __restrict__ rowptr,
                         const int* __restrict__ colv, const float* __restrict__ invd,
                         short* __restrict__ out, int N) {
    const int lane = threadIdx.x & 63;
    const int node = blockIdx.x * 4 + (threadIdx.x >> 6);
    if (node >= N) return;
    int beg = __builtin_amdgcn_readfirstlane(rowptr[node]);
    int end = __builtin_amdgcn_readfirstlane(rowptr[node + 1]);
    const int half = lane >> 5, sub = lane & 31;
    const short* Xs = X + sub * 8;  // 16B chunk within a row

    float acc[8];
#pragma unroll
    for (int c = 0; c < 8; c++) acc[c] = 0.f;

    auto addv = [&](uint4 a) {
        acc[0] += bflo(a.x); acc[1] += bfhi(a.x);
        acc[2] += bflo(a.y); acc[3] += bfhi(a.y);
        acc[4] += bflo(a.z); acc[5] += bfhi(a.z);
        acc[6] += bflo(a.w); acc[7] += bfhi(a.w);
    };

    int j = beg;
    for (; j + 7 < end; j += 8) {
        int i0 = colv[j], i1 = colv[j + 1], i2 = colv[j + 2], i3 = colv[j + 3];
        int i4 = colv[j + 4], i5 = colv[j + 5], i6 = colv[j + 6], i7 = colv[j + 7];
        int sA = half ? i1 : i0;
        int sB = half ? i3 : i2;
        int sC = half ? i5 : i4;
        int sD = half ? i7 : i6;
        uint4 a = *(const uint4*)(Xs + (size_t)sA * 256);
        uint4 b = *(const uint4*)(Xs + (size_t)sB * 256);
        uint4 c = *(const uint4*)(Xs + (size_t)sC * 256);
        uint4 d = *(const uint4*)(Xs + (size_t)sD * 256);
        addv(a); addv(b); addv(c); addv(d);
    }
    if (j + 3 < end) {
        int i0 = colv[j], i1 = colv[j + 1], i2 = colv[j + 2], i3 = colv[j + 3];
        int sA = half ? i1 : i0;
        int sB = half ? i3 : i2;
        uint4 a = *(const uint4*)(Xs + (size_t)sA * 256);
        uint4 b = *(const uint4*)(Xs + (size_t)sB * 256);
        addv(a); addv(b);
        j += 4;
    }
    if (j + 1 < end) {
        int i0 = colv[j], i1 = colv[j + 1];
        int sA = half ? i1 : i0;
        uint4 a = *(const uint4*)(Xs + (size_t)sA * 256);
        addv(a);
        j += 2;
    }
    if (j < end) {
        int i0 = colv[j];
        uint4 a = *(const uint4*)(Xs + (size_t)i0 * 256);
        if (half == 0) addv(a);
    }

#pragma unroll
    for (int c = 0; c < 8; c++) acc[c] += __shfl_xor(acc[c], 32);

    if (half == 0) {
        float sc = invd[node];
        uint4 o;
        o.x = (unsigned)(unsigned short)f2bf(acc[0] * sc) | ((unsigned)(unsigned short)f2bf(acc[1] * sc) << 16);
        o.y = (unsigned)(unsigned short)f2bf(acc[2] * sc) | ((unsigned)(unsigned short)f2bf(acc[3] * sc) << 16);
        o.z = (unsigned)(unsigned short)f2bf(acc[4] * sc) | ((unsigned)(unsigned short)f2bf(acc[5] * sc) << 16);
        o.w = (unsigned)(unsigned short)f2bf(acc[6] * sc) | ((unsigned)(unsigned short)f2bf(acc[7] * sc) << 16);
        *(uint4*)(out + (size_t)node * 256 + sub * 8) = o;
    }
}

// 128-wide CSR mean-agg: quarter-wave owns a neighbor row (16 lanes x 16B),
// 8 neighbors per iter in 2 gathers, combine via shfl_xor(16)+shfl_xor(32).
__launch_bounds__(256)
__global__ void k_agg128(const short* __restrict__ X, const int* __restrict__ rowptr,
                         const int* __restrict__ colv, const float* __restrict__ invd,
                         short* __restrict__ out, int N) {
    const int lane = threadIdx.x & 63;
    const int node = blockIdx.x * 4 + (threadIdx.x >> 6);
    if (node >= N) return;
    int beg = __builtin_amdgcn_readfirstlane(rowptr[node]);
    int end = __builtin_amdgcn_readfirstlane(rowptr[node + 1]);
    const int q = lane >> 4, sub = lane & 15;
    const short* Xs = X + sub * 8;

    float acc[8];
#pragma unroll
    for (int c = 0; c < 8; c++) acc[c] = 0.f;

    auto addv = [&](uint4 a) {
        acc[0] += bflo(a.x); acc[1] += bfhi(a.x);
        acc[2] += bflo(a.y); acc[3] += bfhi(a.y);
        acc[4] += bflo(a.z); acc[5] += bfhi(a.z);
        acc[6] += bflo(a.w); acc[7] += bfhi(a.w);
    };

    int j = beg;
    for (; j + 7 < end; j += 8) {
        int i0 = colv[j], i1 = colv[j + 1], i2 = colv[j + 2], i3 = colv[j + 3];
        int i4 = colv[j + 4], i5 = colv[j + 5], i6 = colv[j + 6], i7 = colv[j + 7];
        int sA = (q == 0) ? i0 : (q == 1) ? i1 : (q == 2) ? i2 : i3;
        int sB = (q == 0) ? i4 : (q == 1) ? i5 : (q == 2) ? i6 : i7;
        uint4 a = *(const uint4*)(Xs + (size_t)sA * 128);
        uint4 b = *(const uint4*)(Xs + (size_t)sB * 128);
        addv(a); addv(b);
    }
    if (j + 3 < end) {
        int i0 = colv[j], i1 = colv[j + 1], i2 = colv[j + 2], i3 = colv[j + 3];
        int sA = (q == 0) ? i0 : (q == 1) ? i1 : (q == 2) ? i2 : i3;
        uint4 a = *(const uint4*)(Xs + (size_t)sA * 128);
        addv(a);
        j += 4;
    }
    int rem = end - j;
    if (rem > 0) {
        int i0 = colv[j];
        int i1 = rem > 1 ? colv[j + 1] : i0;
        int i2 = rem > 2 ? colv[j + 2] : i0;
        int s = (q == 1) ? i1 : (q == 2) ? i2 : i0;
        uint4 a = *(const uint4*)(Xs + (size_t)s * 128);
        if (q < rem) addv(a);
    }

#pragma unroll
    for (int c = 0; c < 8; c++) {
        acc[c] += __shfl_xor(acc[c], 16);
        acc[c] += __shfl_xor(acc[c], 32);
    }

    if (q == 0) {
        float sc = invd[node];
        uint4 o;
        o.x = (unsigned)(unsigned short)f2bf(acc[0] * sc) | ((unsigned)(unsigned short)f2bf(acc[1] * sc) << 16);
        o.y = (unsigned)(unsigned short)f2bf(acc[2] * sc) | ((unsigned)(unsigned short)f2bf(acc[3] * sc) << 16);
        o.z = (unsigned)(unsigned short)f2bf(acc[4] * sc) | ((unsigned)(unsigned short)f2bf(acc[5] * sc) << 16);
        o.w = (unsigned)(unsigned short)f2bf(acc[6] * sc) | ((unsigned)(unsigned short)f2bf(acc[7] * sc) << 16);
        *(uint4*)(out + (size_t)node * 128 + sub * 8) = o;
    }
}

// ---------------------------------------------------------------------------
// LDS-free dual-A bf16 MFMA GEMM (unchanged from round 2)
__launch_bounds__(256)
__global__ void k_gemm_mfma_wide(const short* __restrict__ A1, const short* A2,
                                 const short* __restrict__ P1, const short* __restrict__ P2,
                                 const float* __restrict__ bias,
                                 float* Cf, short* Cb, int M, int K1, int K2) {
    const int lane = threadIdx.x & 63;
    const int wave = threadIdx.x >> 6;
    const int quad = lane >> 4;
    const int r    = lane & 15;
    const int rowBase = blockIdx.x * 64;

    f32x4 acc[4][4];
#pragma unroll
    for (int mt = 0; mt < 4; mt++)
#pragma unroll
        for (int nt = 0; nt < 4; nt++) acc[mt][nt] = (f32x4)(0.f);

    int arow[4];
#pragma unroll
    for (int mt = 0; mt < 4; mt++) {
        int row = rowBase + mt * 16 + r;
        arow[mt] = row < M ? row : M - 1;
    }

    for (int src = 0; src < 2; src++) {
        const short* A = src ? A2 : A1;
        const short* P = src ? P2 : P1;
        const int K = src ? K2 : K1;
        const int nks = K >> 5;
        for (int ks = 0; ks < nks; ks++) {
            bf16x8 af[4], bfr[4];
#pragma unroll
            for (int mt = 0; mt < 4; mt++)
                af[mt] = *(const bf16x8*)(A + (size_t)arow[mt] * K + ks * 32 + quad * 8);
#pragma unroll
            for (int nt = 0; nt < 4; nt++)
                bfr[nt] = *(const bf16x8*)(P + (((size_t)(ks * 16 + wave * 4 + nt) * 64 + lane) << 3));
#pragma unroll
            for (int mt = 0; mt < 4; mt++)
#pragma unroll
                for (int nt = 0; nt < 4; nt++)
                    acc[mt][nt] = __builtin_amdgcn_mfma_f32_16x16x32_bf16(
                        af[mt], bfr[nt], acc[mt][nt], 0, 0, 0);
        }
    }

    __syncthreads();  // guard in-place Cb == A2

    float bv[4];
#pragma unroll
    for (int nt = 0; nt < 4; nt++) bv[nt] = bias[wave * 64 + nt * 16 + r];

#pragma unroll
    for (int mt = 0; mt < 4; mt++) {
#pragma unroll
        for (int reg = 0; reg < 4; reg++) {
            int row = rowBase + mt * 16 + quad * 4 + reg;
            if (row >= M) continue;
#pragma unroll
            for (int nt = 0; nt < 4; nt++) {
                int col = wave * 64 + nt * 16 + r;
                float v = acc[mt][nt][reg] + bv[nt];
                if (Cf) Cf[(size_t)row * 256 + col] = v;
                if (Cb) Cb[(size_t)row * 256 + col] = f2bf(fmaxf(v, 0.f));
            }
        }
    }
}

// Layer-2 fused dual-W MFMA (unchanged from round 2)
__launch_bounds__(256)
__global__ void k_gemm_mfma_out(const short* __restrict__ A,
                                const short* __restrict__ Pl, const short* __restrict__ Pr,
                                const float* __restrict__ bias,
                                short* __restrict__ U, float* __restrict__ Out, int M) {
    const int lane = threadIdx.x & 63;
    const int wave = threadIdx.x >> 6;
    const int quad = lane >> 4;
    const int r    = lane & 15;
    const int rowBase = blockIdx.x * 256 + wave * 64;

    f32x4 aU[4][3], aO[4][3];
#pragma unroll
    for (int mt = 0; mt < 4; mt++)
#pragma unroll
        for (int nt = 0; nt < 3; nt++) { aU[mt][nt] = (f32x4)(0.f); aO[mt][nt] = (f32x4)(0.f); }

    int arow[4];
#pragma unroll
    for (int mt = 0; mt < 4; mt++) {
        int row = rowBase + mt * 16 + r;
        arow[mt] = row < M ? row : M - 1;
    }

    for (int ks = 0; ks < 8; ks++) {
        bf16x8 af[4], bl[3], br[3];
#pragma unroll
        for (int mt = 0; mt < 4; mt++)
            af[mt] = *(const bf16x8*)(A + (size_t)arow[mt] * 256 + ks * 32 + quad * 8);
#pragma unroll
        for (int nt = 0; nt < 3; nt++) {
            size_t fo = (((size_t)(ks * 3 + nt) * 64 + lane) << 3);
            bl[nt] = *(const bf16x8*)(Pl + fo);
            br[nt] = *(const bf16x8*)(Pr + fo);
        }
#pragma unroll
        for (int mt = 0; mt < 4; mt++)
#pragma unroll
            for (int nt = 0; nt < 3; nt++) {
                aU[mt][nt] = __builtin_amdgcn_mfma_f32_16x16x32_bf16(af[mt], bl[nt], aU[mt][nt], 0, 0, 0);
                aO[mt][nt] = __builtin_amdgcn_mfma_f32_16x16x32_bf16(af[mt], br[nt], aO[mt][nt], 0, 0, 0);
            }
    }

    float bv[3];
#pragma unroll
    for (int nt = 0; nt < 3; nt++) {
        int col = nt * 16 + r;
        bv[nt] = (col < DOUT) ? bias[col] : 0.f;
    }

#pragma unroll
    for (int mt = 0; mt < 4; mt++) {
#pragma unroll
        for (int reg = 0; reg < 4; reg++) {
            int row = rowBase + mt * 16 + quad * 4 + reg;
            if (row >= M) continue;
#pragma unroll
            for (int nt = 0; nt < 3; nt++) {
                int col = nt * 16 + r;
                U[(size_t)row * 48 + col] = f2bf(aU[mt][nt][reg]);
                if (col < DOUT) Out[(size_t)row * DOUT + col] = aO[mt][nt][reg] + bv[nt];
            }
        }
    }
}

// out0[dst,:] += inv_deg[dst] * mean-agg of U rows (bf16, stride 48).
// Half-wave per neighbor row: 24 lanes x 4B = 96B, 4 neighbors per iter.
__launch_bounds__(256)
__global__ void k_agg_add47(const short* __restrict__ U, const int* __restrict__ rowptr,
                            const int* __restrict__ colv, const float* __restrict__ invd,
                            float* __restrict__ out0, int N) {
    const int lane = threadIdx.x & 63;
    const int node = blockIdx.x * 4 + (threadIdx.x >> 6);
    if (node >= N) return;
    int beg = __builtin_amdgcn_readfirstlane(rowptr[node]);
    int end = __builtin_amdgcn_readfirstlane(rowptr[node + 1]);
    const int half = lane >> 5, sub = lane & 31;
    const unsigned short* Us = (const unsigned short*)U + sub * 2;
    const bool act = sub < 24;

    float a0 = 0.f, a1 = 0.f;
    int j = beg;
    for (; j + 3 < end; j += 4) {
        int i0 = colv[j], i1 = colv[j + 1], i2 = colv[j + 2], i3 = colv[j + 3];
        int sA = half ? i1 : i0;
        int sB = half ? i3 : i2;
        if (act) {
            unsigned a = *(const unsigned*)(Us + (size_t)sA * 48);
            unsigned b = *(const unsigned*)(Us + (size_t)sB * 48);
            a0 += bflo(a) + bflo(b);
            a1 += bfhi(a) + bfhi(b);
        }
    }
    if (j + 1 < end) {
        int i0 = colv[j], i1 = colv[j + 1];
        int sA = half ? i1 : i0;
        if (act) {
            unsigned a = *(const unsigned*)(Us + (size_t)sA * 48);
            a0 += bflo(a);
            a1 += bfhi(a);
        }
        j += 2;
    }
    if (j < end) {
        int i0 = colv[j];
        if (act) {
            unsigned a = *(const unsigned*)(Us + (size_t)i0 * 48);
            if (half == 0) { a0 += bflo(a); a1 += bfhi(a); }
        }
    }

    a0 += __shfl_xor(a0, 32);
    a1 += __shfl_xor(a1, 32);

    if (half == 0 && act) {
        float sc = invd[node];
        int f0 = sub * 2;
        out0[(size_t)node * DOUT + f0] += sc * a0;
        if (f0 + 1 < DOUT) out0[(size_t)node * DOUT + f0 + 1] += sc * a1;
    }
}

// ---------------------------------------------------------------------------
extern "C" void kernel_launch(void* const* d_in, const int* in_sizes, int n_in,
                              void* d_out, int out_size, void* d_ws, size_t ws_size,
                              hipStream_t stream) {
    const float* x   = (const float*)d_in[0];
    const int*   ei  = (const int*)d_in[1];
    const float* Wl0 = (const float*)d_in[2];
    const float* bl0 = (const float*)d_in[3];
    const float* Wr0 = (const float*)d_in[4];
    const float* Wl1 = (const float*)d_in[5];
    const float* bl1 = (const float*)d_in[6];
    const float* Wr1 = (const float*)d_in[7];
    const float* Wl2 = (const float*)d_in[8];
    const float* bl2 = (const float*)d_in[9];
    const float* Wr2 = (const float*)d_in[10];

    const int N = in_sizes[0] / DIN;
    const int E = in_sizes[1] / 2;

    char* p = (char*)d_ws;
    auto alloc = [&](size_t bytes) -> char* {
        char* r = p;
        p += (bytes + 255) & ~(size_t)255;
        return r;
    };
    int*   flag   = (int*)alloc(4);
    int*   cnt    = (int*)alloc((size_t)N * 4);
    int*   rowptr = (int*)alloc((size_t)(N + 1) * 4);
    int*   csum   = (int*)alloc(1024 * 4);
    int*   colbuf = (int*)alloc((size_t)E * 4 + 64);  // +64: tail s_load slack
    float* invd   = (float*)alloc((size_t)N * 4);
    short* xbf    = (short*)alloc((size_t)N * DIN * 2);   // x bf16; later reused as U [N,48]
    short* bufA   = (short*)alloc((size_t)N * DH * 2);
    short* h0     = (short*)alloc((size_t)N * DH * 2);    // h0 bf16; hrelu in-place after L1
    short* Pl0    = (short*)alloc((size_t)DIN * 256 * 2);
    short* Pr0    = (short*)alloc((size_t)DIN * 256 * 2);
    short* Pl1    = (short*)alloc((size_t)DH * 256 * 2);
    short* Pr1    = (short*)alloc((size_t)DH * 256 * 2);
    short* Pl2    = (short*)alloc((size_t)DH * 48 * 2);
    short* Pr2    = (short*)alloc((size_t)DH * 48 * 2);

    float* out0 = (float*)d_out;                        // [N,47]
    float* hout = (float*)d_out + (size_t)N * DOUT;     // [N,256] fp32 (output 1)

    hipMemsetAsync(flag, 0, 4, stream);
    hipMemsetAsync(cnt, 0, (size_t)N * 4, stream);

    // --- CSR build ---
    const int nprobe = E < 4096 ? E : 4096;
    k_detect<<<(nprobe + 255) / 256, 256, 0, stream>>>(ei, flag, nprobe);
    k_hist<<<(E + 255) / 256, 256, 0, stream>>>(ei, flag, cnt, E);
    const int nchunks = (N + 1023) / 1024;
    k_chunk_sum<<<nchunks, 256, 0, stream>>>(cnt, csum, N);
    k_scan_csum<<<1, 128, 0, stream>>>(csum, nchunks, rowptr, N, E);
    k_scan_apply<<<nchunks, 256, 0, stream>>>(cnt, csum, rowptr, N);
    hipMemsetAsync(cnt, 0, (size_t)N * 4, stream);
    k_fill<<<(E + 255) / 256, 256, 0, stream>>>(ei, flag, rowptr, cnt, colbuf, E);
    k_invdeg<<<(N + 255) / 256, 256, 0, stream>>>(rowptr, invd, N);

    // --- weight packing + x conversion ---
    k_pack<<<(4 * 16 * 64 + 255) / 256, 256, 0, stream>>>(Wl0, Pl0, 4, 16, 256);
    k_pack<<<(4 * 16 * 64 + 255) / 256, 256, 0, stream>>>(Wr0, Pr0, 4, 16, 256);
    k_pack<<<(8 * 16 * 64 + 255) / 256, 256, 0, stream>>>(Wl1, Pl1, 8, 16, 256);
    k_pack<<<(8 * 16 * 64 + 255) / 256, 256, 0, stream>>>(Wr1, Pr1, 8, 16, 256);
    k_pack<<<(8 * 3 * 64 + 255) / 256, 256, 0, stream>>>(Wl2, Pl2, 8, 3, DOUT);
    k_pack<<<(8 * 3 * 64 + 255) / 256, 256, 0, stream>>>(Wr2, Pr2, 8, 3, DOUT);
    k_f2bf<<<((N * DIN / 4) + 255) / 256, 256, 0, stream>>>(x, xbf, N * DIN / 4);

    const int aggBlocks = (N + 3) / 4;
    const int gw = (N + 63) / 64;

    // Layer 0
    k_agg128<<<aggBlocks, 256, 0, stream>>>(xbf, rowptr, colbuf, invd, bufA, N);
    k_gemm_mfma_wide<<<gw, 256, 0, stream>>>(bufA, xbf, Pl0, Pr0, bl0, nullptr, h0,
                                             N, DIN, DIN);

    // Layer 1 (hout = output 1, fp32; hrelu bf16 in-place over h0)
    k_agg256<<<aggBlocks, 256, 0, stream>>>(h0, rowptr, colbuf, invd, bufA, N);
    k_gemm_mfma_wide<<<gw, 256, 0, stream>>>(bufA, h0, Pl1, Pr1, bl1, hout, h0,
                                             N, DH, DH);

    // Layer 2
    short* U = xbf;
    k_gemm_mfma_out<<<(N + 255) / 256, 256, 0, stream>>>(h0, Pl2, Pr2, bl2, U, out0, N);
    k_agg_add47<<<aggBlocks, 256, 0, stream>>>(U, rowptr, colbuf, invd, out0, N);
}

// Round 4
// 720.664 us; speedup vs baseline: 2.1724x; 1.0658x over previous
//
#include <hip/hip_runtime.h>
#include <cstdint>
#include <cstddef>

static constexpr int DIN  = 128;
static constexpr int DH   = 256;
static constexpr int DOUT = 47;

typedef __attribute__((ext_vector_type(8))) short bf16x8;
typedef __attribute__((ext_vector_type(4))) float f32x4;
typedef __attribute__((ext_vector_type(2))) float f32x2;

__device__ __forceinline__ short f2bf(float f) {
    unsigned u = __float_as_uint(f);
    unsigned r = (u + 0x7fffu + ((u >> 16) & 1u)) >> 16;  // RNE
    return (short)r;
}
__device__ __forceinline__ float bflo(unsigned u) { return __uint_as_float(u << 16); }
__device__ __forceinline__ float bfhi(unsigned u) { return __uint_as_float(u & 0xffff0000u); }

// fp8 e4m3 (HW-native) helpers
__device__ __forceinline__ void addpk(unsigned w, float* a) {
    f32x2 lo = __builtin_amdgcn_cvt_pk_f32_fp8(w, false);
    f32x2 hi = __builtin_amdgcn_cvt_pk_f32_fp8(w, true);
    a[0] += lo[0]; a[1] += lo[1]; a[2] += hi[0]; a[3] += hi[1];
}
__device__ __forceinline__ unsigned enc4(float a, float b, float c, float d) {
    unsigned w = __builtin_amdgcn_cvt_pk_fp8_f32(a, b, 0, false);
    w = __builtin_amdgcn_cvt_pk_fp8_f32(c, d, w, true);
    return w;
}
__device__ __forceinline__ unsigned char enc1(float v) {
    return (unsigned char)(__builtin_amdgcn_cvt_pk_fp8_f32(v, v, 0, false) & 0xff);
}
__device__ __forceinline__ unsigned pbf2(float a, float b, float sc) {
    return (unsigned)(unsigned short)f2bf(a * sc) |
           ((unsigned)(unsigned short)f2bf(b * sc) << 16);
}

// ---------------------------------------------------------------------------
// CSR build
__global__ void k_detect(const int* __restrict__ e, int* __restrict__ flag, int nprobe) {
    int i = blockIdx.x * blockDim.x + threadIdx.x;
    if (i < nprobe) {
        if (e[2 * i + 1] != 0) atomicOr(flag, 1);
    }
}

__global__ void k_hist(const int* __restrict__ e, const int* __restrict__ flag,
                       int* __restrict__ cnt, int E) {
    int i = blockIdx.x * blockDim.x + threadIdx.x;
    if (i >= E) return;
    int is32 = *flag;
    int d = is32 ? e[E + i] : e[2 * (E + i)];
    atomicAdd(&cnt[d], 1);
}

__global__ void k_chunk_sum(const int* __restrict__ cnt, int* __restrict__ csum, int n) {
    int base = blockIdx.x * 1024;
    int t = threadIdx.x;
    int s = 0;
#pragma unroll
    for (int j = 0; j < 4; j++) {
        int i = base + t * 4 + j;
        if (i < n) s += cnt[i];
    }
    __shared__ int red[256];
    red[t] = s;
    __syncthreads();
    for (int off = 128; off > 0; off >>= 1) {
        if (t < off) red[t] += red[t + off];
        __syncthreads();
    }
    if (t == 0) csum[blockIdx.x] = red[0];
}

__global__ void k_scan_csum(int* __restrict__ csum, int n,
                            int* __restrict__ rowptr, int N, int E) {
    __shared__ int s[128];
    int t = threadIdx.x;
    int v = (t < n) ? csum[t] : 0;
    s[t] = v;
    __syncthreads();
    for (int off = 1; off < 128; off <<= 1) {
        int xv = (t >= off) ? s[t - off] : 0;
        __syncthreads();
        s[t] += xv;
        __syncthreads();
    }
    if (t < n) csum[t] = s[t] - v;  // exclusive
    if (t == 0) rowptr[N] = E;
}

__global__ void k_scan_apply(const int* __restrict__ cnt, const int* __restrict__ csum,
                             int* __restrict__ rowptr, int n) {
    int base = blockIdx.x * 1024, t = threadIdx.x;
    int i0 = base + t * 4;
    int v[4];
#pragma unroll
    for (int j = 0; j < 4; j++) {
        int i = i0 + j;
        v[j] = (i < n) ? cnt[i] : 0;
    }
    int tsum = v[0] + v[1] + v[2] + v[3];
    __shared__ int s[256];
    s[t] = tsum;
    __syncthreads();
    for (int off = 1; off < 256; off <<= 1) {
        int xv = (t >= off) ? s[t - off] : 0;
        __syncthreads();
        s[t] += xv;
        __syncthreads();
    }
    int excl = s[t] - tsum + csum[blockIdx.x];
#pragma unroll
    for (int j = 0; j < 4; j++) {
        int i = i0 + j;
        if (i < n) rowptr[i] = excl;
        excl += v[j];
    }
}

__global__ void k_fill(const int* __restrict__ e, const int* __restrict__ flag,
                       const int* __restrict__ rowptr, int* __restrict__ cursor,
                       int* __restrict__ colbuf, int E) {
    int i = blockIdx.x * blockDim.x + threadIdx.x;
    if (i >= E) return;
    int is32 = *flag;
    int s = is32 ? e[i] : e[2 * i];
    int d = is32 ? e[E + i] : e[2 * (E + i)];
    int pos = atomicAdd(&cursor[d], 1);
    colbuf[rowptr[d] + pos] = s;
}

__global__ void k_invdeg(const int* __restrict__ rowptr, float* __restrict__ invd, int N) {
    int i = blockIdx.x * blockDim.x + threadIdx.x;
    if (i >= N) return;
    int d = rowptr[i + 1] - rowptr[i];
    invd[i] = 1.0f / (float)(d > 1 ? d : 1);
}

// ---------------------------------------------------------------------------
// fp32 x -> bf16 (GEMM A2) + fp8 (gather table)
__global__ void k_f2bf8(const float* __restrict__ X, short* __restrict__ Yb,
                        unsigned* __restrict__ Y8, int n4) {
    int i = blockIdx.x * 256 + threadIdx.x;
    if (i >= n4) return;
    float4 v = *(const float4*)(X + (size_t)i * 4);
    short4 o;
    o.x = f2bf(v.x); o.y = f2bf(v.y); o.z = f2bf(v.z); o.w = f2bf(v.w);
    *(short4*)(Yb + (size_t)i * 4) = o;
    Y8[i] = enc4(v.x, v.y, v.z, v.w);
}

// Pack fp32 weight [K, Ncols] into bf16 B-fragment order for mfma_16x16x32
__global__ void k_pack(const float* __restrict__ W, short* __restrict__ P,
                       int ksteps, int Nt, int Ncols) {
    int idx = blockIdx.x * 256 + threadIdx.x;
    int total = ksteps * Nt * 64;
    if (idx >= total) return;
    int lane = idx & 63;
    int t = idx >> 6;
    int nt = t % Nt;
    int ks = t / Nt;
    int n = nt * 16 + (lane & 15);
    int kb = ks * 32 + (lane >> 4) * 8;
    bf16x8 o;
#pragma unroll
    for (int j = 0; j < 8; j++)
        o[j] = (n < Ncols) ? f2bf(W[(size_t)(kb + j) * Ncols + n]) : (short)0;
    *(bf16x8*)(P + (size_t)idx * 8) = o;
}

// ---------------------------------------------------------------------------
// 256-wide fp8 CSR mean-agg: quarter-wave owns a row (16 lanes x 16B = 256B),
// 8 neighbors/iter in 2 uint4 gathers. Output bf16 (GEMM A1 input).
__launch_bounds__(256)
__global__ void k_agg256_f8(const unsigned char* __restrict__ X8, const int* __restrict__ rowptr,
                            const int* __restrict__ colv, const float* __restrict__ invd,
                            short* __restrict__ out, int N) {
    const int lane = threadIdx.x & 63;
    const int node = blockIdx.x * 4 + (threadIdx.x >> 6);
    if (node >= N) return;
    int beg = __builtin_amdgcn_readfirstlane(rowptr[node]);
    int end = __builtin_amdgcn_readfirstlane(rowptr[node + 1]);
    const int q = lane >> 4, sub = lane & 15;
    const unsigned char* Xs = X8 + sub * 16;

    float acc[16];
#pragma unroll
    for (int c = 0; c < 16; c++) acc[c] = 0.f;

    auto addv = [&](uint4 a) {
        addpk(a.x, acc); addpk(a.y, acc + 4); addpk(a.z, acc + 8); addpk(a.w, acc + 12);
    };

    int j = beg;
    for (; j + 7 < end; j += 8) {
        int i0 = colv[j], i1 = colv[j + 1], i2 = colv[j + 2], i3 = colv[j + 3];
        int i4 = colv[j + 4], i5 = colv[j + 5], i6 = colv[j + 6], i7 = colv[j + 7];
        int sA = (q == 0) ? i0 : (q == 1) ? i1 : (q == 2) ? i2 : i3;
        int sB = (q == 0) ? i4 : (q == 1) ? i5 : (q == 2) ? i6 : i7;
        uint4 a = *(const uint4*)(Xs + (size_t)sA * 256);
        uint4 b = *(const uint4*)(Xs + (size_t)sB * 256);
        addv(a); addv(b);
    }
    if (j + 3 < end) {
        int i0 = colv[j], i1 = colv[j + 1], i2 = colv[j + 2], i3 = colv[j + 3];
        int sA = (q == 0) ? i0 : (q == 1) ? i1 : (q == 2) ? i2 : i3;
        uint4 a = *(const uint4*)(Xs + (size_t)sA * 256);
        addv(a);
        j += 4;
    }
    int rem = end - j;
    if (rem > 0) {
        int i0 = colv[j];
        int i1 = rem > 1 ? colv[j + 1] : i0;
        int i2 = rem > 2 ? colv[j + 2] : i0;
        int s = (q == 1) ? i1 : (q == 2) ? i2 : i0;
        uint4 a = *(const uint4*)(Xs + (size_t)s * 256);
        if (q < rem) addv(a);
    }

#pragma unroll
    for (int c = 0; c < 16; c++) {
        acc[c] += __shfl_xor(acc[c], 16);
        acc[c] += __shfl_xor(acc[c], 32);
    }

    if (q == 0) {
        float sc = invd[node];
        uint4 o0, o1;
        o0.x = pbf2(acc[0], acc[1], sc);   o0.y = pbf2(acc[2], acc[3], sc);
        o0.z = pbf2(acc[4], acc[5], sc);   o0.w = pbf2(acc[6], acc[7], sc);
        o1.x = pbf2(acc[8], acc[9], sc);   o1.y = pbf2(acc[10], acc[11], sc);
        o1.z = pbf2(acc[12], acc[13], sc); o1.w = pbf2(acc[14], acc[15], sc);
        short* op = out + (size_t)node * 256 + sub * 16;
        *(uint4*)op = o0;
        *(uint4*)(op + 8) = o1;
    }
}

// 128-wide fp8 CSR mean-agg: eighth-wave owns a row (8 lanes x 16B = 128B),
// 16 neighbors/iter in 2 uint4 gathers.
__launch_bounds__(256)
__global__ void k_agg128_f8(const unsigned char* __restrict__ X8, const int* __restrict__ rowptr,
                            const int* __restrict__ colv, const float* __restrict__ invd,
                            short* __restrict__ out, int N) {
    const int lane = threadIdx.x & 63;
    const int node = blockIdx.x * 4 + (threadIdx.x >> 6);
    if (node >= N) return;
    int beg = __builtin_amdgcn_readfirstlane(rowptr[node]);
    int end = __builtin_amdgcn_readfirstlane(rowptr[node + 1]);
    const int grp = lane >> 3, sub = lane & 7;
    const unsigned char* Xs = X8 + sub * 16;

    float acc[16];
#pragma unroll
    for (int c = 0; c < 16; c++) acc[c] = 0.f;

    auto addv = [&](uint4 a) {
        addpk(a.x, acc); addpk(a.y, acc + 4); addpk(a.z, acc + 8); addpk(a.w, acc + 12);
    };

    int j = beg;
    for (; j + 15 < end; j += 16) {
        int sA = colv[j + grp];
        int sB = colv[j + 8 + grp];
        uint4 a = *(const uint4*)(Xs + (size_t)sA * 128);
        uint4 b = *(const uint4*)(Xs + (size_t)sB * 128);
        addv(a); addv(b);
    }
    if (j + 7 < end) {
        int sA = colv[j + grp];
        uint4 a = *(const uint4*)(Xs + (size_t)sA * 128);
        addv(a);
        j += 8;
    }
    int rem = end - j;
    if (rem > 0) {
        int sA = colv[j + (grp < rem ? grp : 0)];
        uint4 a = *(const uint4*)(Xs + (size_t)sA * 128);
        if (grp < rem) addv(a);
    }

#pragma unroll
    for (int c = 0; c < 16; c++) {
        acc[c] += __shfl_xor(acc[c], 8);
        acc[c] += __shfl_xor(acc[c], 16);
        acc[c] += __shfl_xor(acc[c], 32);
    }

    if (grp == 0) {
        float sc = invd[node];
        uint4 o0, o1;
        o0.x = pbf2(acc[0], acc[1], sc);   o0.y = pbf2(acc[2], acc[3], sc);
        o0.z = pbf2(acc[4], acc[5], sc);   o0.w = pbf2(acc[6], acc[7], sc);
        o1.x = pbf2(acc[8], acc[9], sc);   o1.y = pbf2(acc[10], acc[11], sc);
        o1.z = pbf2(acc[12], acc[13], sc); o1.w = pbf2(acc[14], acc[15], sc);
        short* op = out + (size_t)node * 128 + sub * 16;
        *(uint4*)op = o0;
        *(uint4*)(op + 8) = o1;
    }
}

// ---------------------------------------------------------------------------
// LDS-free dual-A bf16 MFMA GEMM; optional fp8 relu copy C8 for the next gather.
__launch_bounds__(256)
__global__ void k_gemm_mfma_wide(const short* __restrict__ A1, const short* A2,
                                 const short* __restrict__ P1, const short* __restrict__ P2,
                                 const float* __restrict__ bias,
                                 float* Cf, short* Cb, unsigned char* C8,
                                 int M, int K1, int K2) {
    const int lane = threadIdx.x & 63;
    const int wave = threadIdx.x >> 6;
    const int quad = lane >> 4;
    const int r    = lane & 15;
    const int rowBase = blockIdx.x * 64;

    f32x4 acc[4][4];
#pragma unroll
    for (int mt = 0; mt < 4; mt++)
#pragma unroll
        for (int nt = 0; nt < 4; nt++) acc[mt][nt] = (f32x4)(0.f);

    int arow[4];
#pragma unroll
    for (int mt = 0; mt < 4; mt++) {
        int row = rowBase + mt * 16 + r;
        arow[mt] = row < M ? row : M - 1;
    }

    for (int src = 0; src < 2; src++) {
        const short* A = src ? A2 : A1;
        const short* P = src ? P2 : P1;
        const int K = src ? K2 : K1;
        const int nks = K >> 5;
        for (int ks = 0; ks < nks; ks++) {
            bf16x8 af[4], bfr[4];
#pragma unroll
            for (int mt = 0; mt < 4; mt++)
                af[mt] = *(const bf16x8*)(A + (size_t)arow[mt] * K + ks * 32 + quad * 8);
#pragma unroll
            for (int nt = 0; nt < 4; nt++)
                bfr[nt] = *(const bf16x8*)(P + (((size_t)(ks * 16 + wave * 4 + nt) * 64 + lane) << 3));
#pragma unroll
            for (int mt = 0; mt < 4; mt++)
#pragma unroll
                for (int nt = 0; nt < 4; nt++)
                    acc[mt][nt] = __builtin_amdgcn_mfma_f32_16x16x32_bf16(
                        af[mt], bfr[nt], acc[mt][nt], 0, 0, 0);
        }
    }

    __syncthreads();  // guard in-place Cb == A2

    float bv[4];
#pragma unroll
    for (int nt = 0; nt < 4; nt++) bv[nt] = bias[wave * 64 + nt * 16 + r];

#pragma unroll
    for (int mt = 0; mt < 4; mt++) {
#pragma unroll
        for (int reg = 0; reg < 4; reg++) {
            int row = rowBase + mt * 16 + quad * 4 + reg;
            if (row >= M) continue;
#pragma unroll
            for (int nt = 0; nt < 4; nt++) {
                int col = wave * 64 + nt * 16 + r;
                float v = acc[mt][nt][reg] + bv[nt];
                if (Cf) Cf[(size_t)row * 256 + col] = v;
                if (Cb) Cb[(size_t)row * 256 + col] = f2bf(fmaxf(v, 0.f));
                if (C8) C8[(size_t)row * 256 + col] = enc1(fmaxf(v, 0.f));
            }
        }
    }
}

// Layer-2 fused dual-W MFMA: U (fp8, stride 48) + Out (fp32, [M,47])
__launch_bounds__(256)
__global__ void k_gemm_mfma_out(const short* __restrict__ A,
                                const short* __restrict__ Pl, const short* __restrict__ Pr,
                                const float* __restrict__ bias,
                                unsigned char* __restrict__ U8, float* __restrict__ Out, int M) {
    const int lane = threadIdx.x & 63;
    const int wave = threadIdx.x >> 6;
    const int quad = lane >> 4;
    const int r    = lane & 15;
    const int rowBase = blockIdx.x * 256 + wave * 64;

    f32x4 aU[4][3], aO[4][3];
#pragma unroll
    for (int mt = 0; mt < 4; mt++)
#pragma unroll
        for (int nt = 0; nt < 3; nt++) { aU[mt][nt] = (f32x4)(0.f); aO[mt][nt] = (f32x4)(0.f); }

    int arow[4];
#pragma unroll
    for (int mt = 0; mt < 4; mt++) {
        int row = rowBase + mt * 16 + r;
        arow[mt] = row < M ? row : M - 1;
    }

    for (int ks = 0; ks < 8; ks++) {
        bf16x8 af[4], bl[3], br[3];
#pragma unroll
        for (int mt = 0; mt < 4; mt++)
            af[mt] = *(const bf16x8*)(A + (size_t)arow[mt] * 256 + ks * 32 + quad * 8);
#pragma unroll
        for (int nt = 0; nt < 3; nt++) {
            size_t fo = (((size_t)(ks * 3 + nt) * 64 + lane) << 3);
            bl[nt] = *(const bf16x8*)(Pl + fo);
            br[nt] = *(const bf16x8*)(Pr + fo);
        }
#pragma unroll
        for (int mt = 0; mt < 4; mt++)
#pragma unroll
            for (int nt = 0; nt < 3; nt++) {
                aU[mt][nt] = __builtin_amdgcn_mfma_f32_16x16x32_bf16(af[mt], bl[nt], aU[mt][nt], 0, 0, 0);
                aO[mt][nt] = __builtin_amdgcn_mfma_f32_16x16x32_bf16(af[mt], br[nt], aO[mt][nt], 0, 0, 0);
            }
    }

    float bv[3];
#pragma unroll
    for (int nt = 0; nt < 3; nt++) {
        int col = nt * 16 + r;
        bv[nt] = (col < DOUT) ? bias[col] : 0.f;
    }

#pragma unroll
    for (int mt = 0; mt < 4; mt++) {
#pragma unroll
        for (int reg = 0; reg < 4; reg++) {
            int row = rowBase + mt * 16 + quad * 4 + reg;
            if (row >= M) continue;
#pragma unroll
            for (int nt = 0; nt < 3; nt++) {
                int col = nt * 16 + r;
                U8[(size_t)row * 48 + col] = enc1(aU[mt][nt][reg]);
                if (col < DOUT) Out[(size_t)row * DOUT + col] = aO[mt][nt][reg] + bv[nt];
            }
        }
    }
}

// out0[dst,:] += inv_deg[dst] * mean-agg of U8 rows (fp8, stride 48).
// Quarter-wave per row: 12 active lanes x 4B = 48B; 8 neighbors/iter, 2 gathers.
__launch_bounds__(256)
__global__ void k_agg_add47_f8(const unsigned char* __restrict__ U8, const int* __restrict__ rowptr,
                               const int* __restrict__ colv, const float* __restrict__ invd,
                               float* __restrict__ out0, int N) {
    const int lane = threadIdx.x & 63;
    const int node = blockIdx.x * 4 + (threadIdx.x >> 6);
    if (node >= N) return;
    int beg = __builtin_amdgcn_readfirstlane(rowptr[node]);
    int end = __builtin_amdgcn_readfirstlane(rowptr[node + 1]);
    const int q = lane >> 4, sub = lane & 15;
    const bool act = sub < 12;
    const unsigned char* Us = U8 + sub * 4;

    float acc[4] = {0.f, 0.f, 0.f, 0.f};

    int j = beg;
    for (; j + 7 < end; j += 8) {
        int i0 = colv[j], i1 = colv[j + 1], i2 = colv[j + 2], i3 = colv[j + 3];
        int i4 = colv[j + 4], i5 = colv[j + 5], i6 = colv[j + 6], i7 = colv[j + 7];
        int sA = (q == 0) ? i0 : (q == 1) ? i1 : (q == 2) ? i2 : i3;
        int sB = (q == 0) ? i4 : (q == 1) ? i5 : (q == 2) ? i6 : i7;
        if (act) {
            unsigned a = *(const unsigned*)(Us + (size_t)sA * 48);
            unsigned b = *(const unsigned*)(Us + (size_t)sB * 48);
            addpk(a, acc); addpk(b, acc);
        }
    }
    if (j + 3 < end) {
        int i0 = colv[j], i1 = colv[j + 1], i2 = colv[j + 2], i3 = colv[j + 3];
        int sA = (q == 0) ? i0 : (q == 1) ? i1 : (q == 2) ? i2 : i3;
        if (act) {
            unsigned a = *(const unsigned*)(Us + (size_t)sA * 48);
            addpk(a, acc);
        }
        j += 4;
    }
    int rem = end - j;
    if (rem > 0) {
        int i0 = colv[j];
        int i1 = rem > 1 ? colv[j + 1] : i0;
        int i2 = rem > 2 ? colv[j + 2] : i0;
        int s = (q == 1) ? i1 : (q == 2) ? i2 : i0;
        if (act && q < rem) {
            unsigned a = *(const unsigned*)(Us + (size_t)s * 48);
            addpk(a, acc);
        }
    }

#pragma unroll
    for (int c = 0; c < 4; c++) {
        acc[c] += __shfl_xor(acc[c], 16);
        acc[c] += __shfl_xor(acc[c], 32);
    }

    if (q == 0 && act) {
        float sc = invd[node];
        int f0 = sub * 4;
        float* op = out0 + (size_t)node * DOUT;
#pragma unroll
        for (int c = 0; c < 4; c++)
            if (f0 + c < DOUT) op[f0 + c] += sc * acc[c];
    }
}

// ---------------------------------------------------------------------------
extern "C" void kernel_launch(void* const* d_in, const int* in_sizes, int n_in,
                              void* d_out, int out_size, void* d_ws, size_t ws_size,
                              hipStream_t stream) {
    const float* x   = (const float*)d_in[0];
    const int*   ei  = (const int*)d_in[1];
    const float* Wl0 = (const float*)d_in[2];
    const float* bl0 = (const float*)d_in[3];
    const float* Wr0 = (const float*)d_in[4];
    const float* Wl1 = (const float*)d_in[5];
    const float* bl1 = (const float*)d_in[6];
    const float* Wr1 = (const float*)d_in[7];
    const float* Wl2 = (const float*)d_in[8];
    const float* bl2 = (const float*)d_in[9];
    const float* Wr2 = (const float*)d_in[10];

    const int N = in_sizes[0] / DIN;
    const int E = in_sizes[1] / 2;

    char* p = (char*)d_ws;
    auto alloc = [&](size_t bytes) -> char* {
        char* r = p;
        p += (bytes + 255) & ~(size_t)255;
        return r;
    };
    int*   flag   = (int*)alloc(4);
    int*   cnt    = (int*)alloc((size_t)N * 4);
    int*   rowptr = (int*)alloc((size_t)(N + 1) * 4);
    int*   csum   = (int*)alloc(1024 * 4);
    int*   colbuf = (int*)alloc((size_t)E * 4 + 64);
    float* invd   = (float*)alloc((size_t)N * 4);
    short* xbf    = (short*)alloc((size_t)N * DIN * 2);   // x bf16; later reused as U8 [N,48] fp8
    short* bufA   = (short*)alloc((size_t)N * DH * 2);    // agg output (bf16, GEMM A1)
    short* h0     = (short*)alloc((size_t)N * DH * 2);    // h0 bf16; hrelu in-place after L1
    unsigned*      x8 = (unsigned*)alloc((size_t)N * DIN);      // fp8 x (gather table)
    unsigned char* h8 = (unsigned char*)alloc((size_t)N * DH);  // fp8 relu(h0) (gather table)
    short* Pl0    = (short*)alloc((size_t)DIN * 256 * 2);
    short* Pr0    = (short*)alloc((size_t)DIN * 256 * 2);
    short* Pl1    = (short*)alloc((size_t)DH * 256 * 2);
    short* Pr1    = (short*)alloc((size_t)DH * 256 * 2);
    short* Pl2    = (short*)alloc((size_t)DH * 48 * 2);
    short* Pr2    = (short*)alloc((size_t)DH * 48 * 2);

    float* out0 = (float*)d_out;                        // [N,47]
    float* hout = (float*)d_out + (size_t)N * DOUT;     // [N,256] fp32 (output 1)

    hipMemsetAsync(flag, 0, 4, stream);
    hipMemsetAsync(cnt, 0, (size_t)N * 4, stream);

    // --- CSR build ---
    const int nprobe = E < 4096 ? E : 4096;
    k_detect<<<(nprobe + 255) / 256, 256, 0, stream>>>(ei, flag, nprobe);
    k_hist<<<(E + 255) / 256, 256, 0, stream>>>(ei, flag, cnt, E);
    const int nchunks = (N + 1023) / 1024;
    k_chunk_sum<<<nchunks, 256, 0, stream>>>(cnt, csum, N);
    k_scan_csum<<<1, 128, 0, stream>>>(csum, nchunks, rowptr, N, E);
    k_scan_apply<<<nchunks, 256, 0, stream>>>(cnt, csum, rowptr, N);
    hipMemsetAsync(cnt, 0, (size_t)N * 4, stream);
    k_fill<<<(E + 255) / 256, 256, 0, stream>>>(ei, flag, rowptr, cnt, colbuf, E);
    k_invdeg<<<(N + 255) / 256, 256, 0, stream>>>(rowptr, invd, N);

    // --- weight packing + x conversion ---
    k_pack<<<(4 * 16 * 64 + 255) / 256, 256, 0, stream>>>(Wl0, Pl0, 4, 16, 256);
    k_pack<<<(4 * 16 * 64 + 255) / 256, 256, 0, stream>>>(Wr0, Pr0, 4, 16, 256);
    k_pack<<<(8 * 16 * 64 + 255) / 256, 256, 0, stream>>>(Wl1, Pl1, 8, 16, 256);
    k_pack<<<(8 * 16 * 64 + 255) / 256, 256, 0, stream>>>(Wr1, Pr1, 8, 16, 256);
    k_pack<<<(8 * 3 * 64 + 255) / 256, 256, 0, stream>>>(Wl2, Pl2, 8, 3, DOUT);
    k_pack<<<(8 * 3 * 64 + 255) / 256, 256, 0, stream>>>(Wr2, Pr2, 8, 3, DOUT);
    k_f2bf8<<<((N * DIN / 4) + 255) / 256, 256, 0, stream>>>(x, xbf, x8, N * DIN / 4);

    const int aggBlocks = (N + 3) / 4;
    const int gw = (N + 63) / 64;

    // Layer 0: h0 = bf16(relu(...)), h8 = fp8(relu(...))
    k_agg128_f8<<<aggBlocks, 256, 0, stream>>>((const unsigned char*)x8, rowptr, colbuf, invd, bufA, N);
    k_gemm_mfma_wide<<<gw, 256, 0, stream>>>(bufA, xbf, Pl0, Pr0, bl0,
                                             nullptr, h0, h8, N, DIN, DIN);

    // Layer 1: hout fp32 (output 1); hrelu bf16 in-place over h0
    k_agg256_f8<<<aggBlocks, 256, 0, stream>>>(h8, rowptr, colbuf, invd, bufA, N);
    k_gemm_mfma_wide<<<gw, 256, 0, stream>>>(bufA, h0, Pl1, Pr1, bl1,
                                             hout, h0, nullptr, N, DH, DH);

    // Layer 2: U8 = fp8(hrelu@Wl2), out0 = hrelu@Wr2 + bl2; out0 += agg(U8)
    unsigned char* U8 = (unsigned char*)xbf;  // xbf dead after L0 GEMM
    k_gemm_mfma_out<<<(N + 255) / 256, 256, 0, stream>>>(h0, Pl2, Pr2, bl2, U8, out0, N);
    k_agg_add47_f8<<<aggBlocks, 256, 0, stream>>>(U8, rowptr, colbuf, invd, out0, N);
}